// Round 9
// baseline (71.959 us; speedup 1.0000x reference)
//
#include <hip/hip_runtime.h>

#define BIG 1e9f

// ---- asm macros -----------------------------------------------------------
// RD2(W): running unclamped LDS byte addr au += 256 (next row); clamp to
//         [row0, row63] with one med3 (sb = base+lane*4, hi = sb+63*256);
//         issue ds_read_b32 for diag k+12.
#define RD2(W) \
    "v_add_u32 %[au], 0x100, %[au]\n\t" \
    "v_med3_i32 %[ad], %[au], %[sb], %[hi]\n\t" \
    "ds_read_b32 " W ", %[ad]\n\t"

// CM2(W,XW,XS): x = wave_shr:1(e). No bound_ctrl => lane 0 dest is PRESERVED,
// and since XW/XS are only ever written by this DPP, lane 0 keeps its initial
// BIG forever (no per-slot re-init needed). Then e = min3(left,up,diag) + w.
#define CM2(W, XW, XS) \
    "v_mov_b32_dpp " XW ", %[e] wave_shr:1 row_mask:0xf bank_mask:0xf\n\t" \
    "v_min3_f32 %[tp], " XW ", %[e], " XS "\n\t" \
    "v_add_f32 %[e], %[tp], " W "\n\t"

// One waitcnt per TWO slots: 12 ds_reads outstanding; lgkmcnt(10) retires the
// two oldest (in-order DS), covering both slots' consumed w regs.
#define PAIR(WiA, WcA, WiB, WcB, XN, XO) \
    "s_waitcnt lgkmcnt(10)\n\t" \
    RD2(WiA) CM2(WcA, XN, XO) \
    RD2(WiB) CM2(WcB, XO, XN)

// One asm statement = 14 DP slots (7 pairs); slot issues the read for diag
// k+12 into w[(s+12)%14] and consumes w[s%14]; x0/x1 alternate per slot.
#define BODY14 \
    asm volatile( \
        PAIR("%[w13]", "%[w1]",  "%[w0]",  "%[w2]",  "%[x0]", "%[x1]") \
        PAIR("%[w1]",  "%[w3]",  "%[w2]",  "%[w4]",  "%[x0]", "%[x1]") \
        PAIR("%[w3]",  "%[w5]",  "%[w4]",  "%[w6]",  "%[x0]", "%[x1]") \
        PAIR("%[w5]",  "%[w7]",  "%[w6]",  "%[w8]",  "%[x0]", "%[x1]") \
        PAIR("%[w7]",  "%[w9]",  "%[w8]",  "%[w10]", "%[x0]", "%[x1]") \
        PAIR("%[w9]",  "%[w11]", "%[w10]", "%[w12]", "%[x0]", "%[x1]") \
        PAIR("%[w11]", "%[w13]", "%[w12]", "%[w0]",  "%[x0]", "%[x1]") \
        : [e]"+v"(e), [x0]"+v"(x0), [x1]"+v"(x1), [tp]"+v"(tp), \
          [au]"+v"(au), [ad]"+v"(ad), \
          [w0]"+v"(w0), [w1]"+v"(w1), [w2]"+v"(w2), [w3]"+v"(w3), \
          [w4]"+v"(w4), [w5]"+v"(w5), [w6]"+v"(w6), [w7]"+v"(w7), \
          [w8]"+v"(w8), [w9]"+v"(w9), [w10]"+v"(w10), [w11]"+v"(w11), \
          [w12]"+v"(w12), [w13]"+v"(w13) \
        : [sb]"v"(sb), [hi]"v"(hi) \
        : "memory")

// ONE 64-thread block = ONE wave = ONE sample (2048 independent blocks).
// Single-wave blocks dispatch/retire independently, keeping the global read
// queue full through ramp-up and drain (128-thread blocks coupled wave pairs).
// Anti-diagonal sweep with potential transform e[v] = d[v] + img[v]/2:
//   e[v] = img[v] + min3(e_left, e_up, e_diag);  out = e_final - img[63][63]/2.
// Staging: 16x global_load_lds dwordx4 (direct HBM->LDS), gated into the DP
// with counted s_waitcnt vmcnt(N) so compute overlaps the read phase.
__global__ __launch_bounds__(64) void dp_diag_kernel(const float* __restrict__ img,
                                                     float* __restrict__ out, int B) {
    __shared__ __align__(16) float s[4096];   // 16 KB, wave-private
    const int lane = threadIdx.x;             // 0..63
    const int b = blockIdx.x;
    if (b >= B) return;

    {   // async staging: chunk t = rows 4t..4t+3; lane covers 16 B at lane*4 floats
        const float* g = img + ((size_t)b << 12) + (lane << 2);
        #pragma unroll
        for (int t = 0; t < 16; ++t)
            __builtin_amdgcn_global_load_lds(
                (const __attribute__((address_space(1))) void*)(g + (t << 8)),
                (__attribute__((address_space(3))) void*)(s + (t << 8)),
                16, 0, 0);
    }
    asm volatile("s_waitcnt vmcnt(12)\n\t" ::: "memory");  // t=0..3 done: rows 0..15

    float e  = (lane == 0) ? 0.5f * s[0] : BIG;   // diag k=0 state
    float x0 = BIG, x1 = BIG;   // written ONLY by lane-0-preserving DPP => lane0 stays BIG
    float w0 = 0, w1 = 0, w2 = 0, w3 = 0, w4 = 0, w5 = 0, w6 = 0,
          w7 = 0, w8 = 0, w9 = 0, w10 = 0, w11 = 0, w12 = 0, w13 = 0;
    float tp = 0;
    const int sb = (int)(unsigned)(uintptr_t)s + (lane << 2);  // row-0 byte addr
    const int hi = sb + 16128;                                 // row-63 byte addr
    int au = sb - (lane << 8);   // unclamped addr for diag 0 (pre-increment)
    int ad = 0;

    // prologue: issue ds_reads for diagonals k = 1..12 (rows <= 12) into w1..w12
    asm volatile(
        RD2("%[w1]") RD2("%[w2]") RD2("%[w3]") RD2("%[w4]") RD2("%[w5]") RD2("%[w6]")
        RD2("%[w7]") RD2("%[w8]") RD2("%[w9]") RD2("%[w10]") RD2("%[w11]") RD2("%[w12]")
        "s_nop 2\n\t"
        : [au]"+v"(au), [ad]"+v"(ad),
          [w1]"+v"(w1), [w2]"+v"(w2), [w3]"+v"(w3), [w4]"+v"(w4),
          [w5]"+v"(w5), [w6]"+v"(w6), [w7]"+v"(w7), [w8]"+v"(w8),
          [w9]"+v"(w9), [w10]"+v"(w10), [w11]"+v"(w11), [w12]"+v"(w12)
        : [sb]"v"(sb), [hi]"v"(hi)
        : "memory");

    // body blocks gated on staging progress (block issues reads up to row k0+25):
    asm volatile("s_waitcnt vmcnt(9)\n\t" ::: "memory");  // rows<=27 resident
    BODY14;                                               // k = 1..14
    asm volatile("s_waitcnt vmcnt(5)\n\t" ::: "memory");  // rows<=43 resident
    BODY14;                                               // k = 15..28
    asm volatile("s_waitcnt vmcnt(2)\n\t" ::: "memory");  // rows<=55 resident
    BODY14;                                               // k = 29..42
    asm volatile("s_waitcnt vmcnt(0)\n\t" ::: "memory");  // all rows resident
    BODY14;                                               // k = 43..56
    #pragma unroll 1
    for (int it = 0; it < 5; ++it)                        // k = 57..126
        BODY14;
    asm volatile("s_waitcnt lgkmcnt(0)\n\t" ::: "memory"); // drain 12 dangling reads

    if (lane == 63) out[b] = e - 0.5f * s[4095];  // d[63][63]
}

extern "C" void kernel_launch(void* const* d_in, const int* in_sizes, int n_in,
                              void* d_out, int out_size, void* d_ws, size_t ws_size,
                              hipStream_t stream) {
    const float* img = (const float*)d_in[0];
    float* out = (float*)d_out;
    const int B = out_size;                  // 2048
    dp_diag_kernel<<<B, 64, 0, stream>>>(img, out, B);
}

// Round 11
// 71.210 us; speedup vs baseline: 1.0105x; 1.0105x over previous
//
#include <hip/hip_runtime.h>

#define BIG 1e9f

typedef float f4 __attribute__((ext_vector_type(4)));

// ---- DP asm macros (unchanged from R8) ------------------------------------
// RD2(W): running unclamped LDS byte addr au += 256 (next row); clamp to
//         [row0, row63] with one med3; issue ds_read_b32 for diag k+12.
#define RD2(W) \
    "v_add_u32 %[au], 0x100, %[au]\n\t" \
    "v_med3_i32 %[ad], %[au], %[sb], %[hi]\n\t" \
    "ds_read_b32 " W ", %[ad]\n\t"

// CM2(W,XW,XS): x = wave_shr:1(e); lane 0 dest PRESERVED (stays BIG forever).
#define CM2(W, XW, XS) \
    "v_mov_b32_dpp " XW ", %[e] wave_shr:1 row_mask:0xf bank_mask:0xf\n\t" \
    "v_min3_f32 %[tp], " XW ", %[e], " XS "\n\t" \
    "v_add_f32 %[e], %[tp], " W "\n\t"

// 12 ds_reads stay outstanding; lgkmcnt(10) retires the two oldest (in-order
// DS). Interleaved ds_writes only inflate the count => strictly conservative.
#define PAIR(WiA, WcA, WiB, WcB, XN, XO) \
    "s_waitcnt lgkmcnt(10)\n\t" \
    RD2(WiA) CM2(WcA, XN, XO) \
    RD2(WiB) CM2(WcB, XO, XN)

#define BODY14 \
    asm volatile( \
        PAIR("%[w13]", "%[w1]",  "%[w0]",  "%[w2]",  "%[x0]", "%[x1]") \
        PAIR("%[w1]",  "%[w3]",  "%[w2]",  "%[w4]",  "%[x0]", "%[x1]") \
        PAIR("%[w3]",  "%[w5]",  "%[w4]",  "%[w6]",  "%[x0]", "%[x1]") \
        PAIR("%[w5]",  "%[w7]",  "%[w6]",  "%[w8]",  "%[x0]", "%[x1]") \
        PAIR("%[w7]",  "%[w9]",  "%[w8]",  "%[w10]", "%[x0]", "%[x1]") \
        PAIR("%[w9]",  "%[w11]", "%[w10]", "%[w12]", "%[x0]", "%[x1]") \
        PAIR("%[w11]", "%[w13]", "%[w12]", "%[w0]",  "%[x0]", "%[x1]") \
        : [e]"+v"(e), [x0]"+v"(x0), [x1]"+v"(x1), [tp]"+v"(tp), \
          [au]"+v"(au), [ad]"+v"(ad), \
          [w0]"+v"(w0), [w1]"+v"(w1), [w2]"+v"(w2), [w3]"+v"(w3), \
          [w4]"+v"(w4), [w5]"+v"(w5), [w6]"+v"(w6), [w7]"+v"(w7), \
          [w8]"+v"(w8), [w9]"+v"(w9), [w10]"+v"(w10), [w11]"+v"(w11), \
          [w12]"+v"(w12), [w13]"+v"(w13) \
        : [sb]"v"(sb), [hi]"v"(hi) \
        : "memory")

// One 64-lane wave per sample (2 waves / 128-thread block); lane j = column j.
// Anti-diagonal sweep, potential transform e[v] = d[v] + img[v]/2:
//   e[v] = img[v] + min3(e_left, e_up, e_diag);  out = e_final - img[63][63]/2.
// STAGING: 16 global_load_dwordx4 issued back-to-back into 64 VGPRs (all 16
// in flight per wave; "=&v" early-clobber keeps outputs disjoint from the
// async-written address regs — R10's fault), then drained to LDS with counted
// vmcnt waits interleaved with DP bodies so compute overlaps the read stream.
__global__ __launch_bounds__(128) void dp_diag_kernel(const float* __restrict__ img,
                                                      float* __restrict__ out, int B) {
    __shared__ __align__(16) float smem[2][4096];   // 16 KB per wave, wave-private
    const int lane = threadIdx.x & 63;
    const int wave = threadIdx.x >> 6;
    const int b = (blockIdx.x << 1) + wave;
    if (b >= B) return;                // uniform per wave; no block barrier used

    float* s = smem[wave];
    // chunk t = rows 4t..4t+3 (1 KB); lane covers 16 B at byte 16*lane of chunk
    const char* g0 = (const char*)(img + ((size_t)b << 12)) + (lane << 4);
    const char* g1 = g0 + 4096;
    const char* g2 = g0 + 8192;
    const char* g3 = g0 + 12288;
    f4 c0, c1, c2, c3, c4, c5, c6, c7, c8, c9, c10, c11, c12, c13, c14, c15;

    // 16 loads, no intervening waits: all 16 in flight per wave.
    // "=&v" (early-clobber): no output tuple may alias g0..g3 or another
    // output — loads retire asynchronously, so aliasing faults (R10 bug).
    asm volatile(
        "global_load_dwordx4 %[c0], %[g0], off\n\t"
        "global_load_dwordx4 %[c1], %[g0], off offset:1024\n\t"
        "global_load_dwordx4 %[c2], %[g0], off offset:2048\n\t"
        "global_load_dwordx4 %[c3], %[g0], off offset:3072\n\t"
        "global_load_dwordx4 %[c4], %[g1], off\n\t"
        "global_load_dwordx4 %[c5], %[g1], off offset:1024\n\t"
        "global_load_dwordx4 %[c6], %[g1], off offset:2048\n\t"
        "global_load_dwordx4 %[c7], %[g1], off offset:3072\n\t"
        "global_load_dwordx4 %[c8], %[g2], off\n\t"
        "global_load_dwordx4 %[c9], %[g2], off offset:1024\n\t"
        "global_load_dwordx4 %[c10], %[g2], off offset:2048\n\t"
        "global_load_dwordx4 %[c11], %[g2], off offset:3072\n\t"
        "global_load_dwordx4 %[c12], %[g3], off\n\t"
        "global_load_dwordx4 %[c13], %[g3], off offset:1024\n\t"
        "global_load_dwordx4 %[c14], %[g3], off offset:2048\n\t"
        "global_load_dwordx4 %[c15], %[g3], off offset:3072\n\t"
        : [c0]"=&v"(c0), [c1]"=&v"(c1), [c2]"=&v"(c2), [c3]"=&v"(c3),
          [c4]"=&v"(c4), [c5]"=&v"(c5), [c6]"=&v"(c6), [c7]"=&v"(c7),
          [c8]"=&v"(c8), [c9]"=&v"(c9), [c10]"=&v"(c10), [c11]"=&v"(c11),
          [c12]"=&v"(c12), [c13]"=&v"(c13), [c14]"=&v"(c14), [c15]"=&v"(c15)
        : [g0]"v"(g0), [g1]"v"(g1), [g2]"v"(g2), [g3]"v"(g3)
        : "memory");

    const int lw = (int)(unsigned)(uintptr_t)s + (lane << 4);  // LDS write base
    // drain chunks 0..5 (rows 0..23) as they arrive (in-order vmcnt retire)
    asm volatile(
        "s_waitcnt vmcnt(10)\n\t"
        "ds_write_b128 %[lw], %[c0]\n\t"
        "ds_write_b128 %[lw], %[c1] offset:1024\n\t"
        "ds_write_b128 %[lw], %[c2] offset:2048\n\t"
        "ds_write_b128 %[lw], %[c3] offset:3072\n\t"
        "ds_write_b128 %[lw], %[c4] offset:4096\n\t"
        "ds_write_b128 %[lw], %[c5] offset:5120\n\t"
        :: [lw]"v"(lw), [c0]"v"(c0), [c1]"v"(c1), [c2]"v"(c2),
           [c3]"v"(c3), [c4]"v"(c4), [c5]"v"(c5)
        : "memory");

    // e(0,0) needs img[0][0]: lane 0 holds it in c0.x (valid: c0 retired by
    // the vmcnt(10) above). Only lane 0 uses it — no broadcast needed.
    float e  = (lane == 0) ? 0.5f * c0.x : BIG;
    float x0 = BIG, x1 = BIG;   // written ONLY by lane-0-preserving DPP
    float w0 = 0, w1 = 0, w2 = 0, w3 = 0, w4 = 0, w5 = 0, w6 = 0,
          w7 = 0, w8 = 0, w9 = 0, w10 = 0, w11 = 0, w12 = 0, w13 = 0;
    float tp = 0;
    const int sb = (int)(unsigned)(uintptr_t)s + (lane << 2);  // row-0 read addr
    const int hi = sb + 16128;                                 // row-63 read addr
    int au = sb - (lane << 8);   // unclamped addr for diag 0 (pre-increment)
    int ad = 0;

    // prologue: ds_reads for diagonals k = 1..12 (rows <= 12, chunks <= 3)
    asm volatile(
        RD2("%[w1]") RD2("%[w2]") RD2("%[w3]") RD2("%[w4]") RD2("%[w5]") RD2("%[w6]")
        RD2("%[w7]") RD2("%[w8]") RD2("%[w9]") RD2("%[w10]") RD2("%[w11]") RD2("%[w12]")
        "s_nop 2\n\t"
        : [au]"+v"(au), [ad]"+v"(ad),
          [w1]"+v"(w1), [w2]"+v"(w2), [w3]"+v"(w3), [w4]"+v"(w4),
          [w5]"+v"(w5), [w6]"+v"(w6), [w7]"+v"(w7), [w8]"+v"(w8),
          [w9]"+v"(w9), [w10]"+v"(w10), [w11]"+v"(w11), [w12]"+v"(w12)
        : [sb]"v"(sb), [hi]"v"(hi)
        : "memory");

    // body1 issues reads to row <= 26 -> chunk 6 must be in LDS first
    asm volatile("s_waitcnt vmcnt(9)\n\t"
                 "ds_write_b128 %[lw], %[c6] offset:6144\n\t"
                 :: [lw]"v"(lw), [c6]"v"(c6) : "memory");
    BODY14;                                               // k = 1..14
    // body2 reads to row <= 40 -> chunks 7..10
    asm volatile("s_waitcnt vmcnt(5)\n\t"
                 "ds_write_b128 %[lw], %[c7] offset:7168\n\t"
                 "ds_write_b128 %[lw], %[c8] offset:8192\n\t"
                 "ds_write_b128 %[lw], %[c9] offset:9216\n\t"
                 "ds_write_b128 %[lw], %[c10] offset:10240\n\t"
                 :: [lw]"v"(lw), [c7]"v"(c7), [c8]"v"(c8),
                    [c9]"v"(c9), [c10]"v"(c10) : "memory");
    BODY14;                                               // k = 15..28
    // body3 reads to row <= 54 -> chunks 11..13
    asm volatile("s_waitcnt vmcnt(2)\n\t"
                 "ds_write_b128 %[lw], %[c11] offset:11264\n\t"
                 "ds_write_b128 %[lw], %[c12] offset:12288\n\t"
                 "ds_write_b128 %[lw], %[c13] offset:13312\n\t"
                 :: [lw]"v"(lw), [c11]"v"(c11), [c12]"v"(c12),
                    [c13]"v"(c13) : "memory");
    BODY14;                                               // k = 29..42
    // body4+ read to row 63 -> chunks 14,15
    asm volatile("s_waitcnt vmcnt(0)\n\t"
                 "ds_write_b128 %[lw], %[c14] offset:14336\n\t"
                 "ds_write_b128 %[lw], %[c15] offset:15360\n\t"
                 :: [lw]"v"(lw), [c14]"v"(c14), [c15]"v"(c15) : "memory");
    BODY14;                                               // k = 43..56
    #pragma unroll 1
    for (int it = 0; it < 5; ++it)                        // k = 57..126
        BODY14;
    asm volatile("s_waitcnt lgkmcnt(0)\n\t" ::: "memory"); // drain 12 dangling reads

    if (lane == 63) out[b] = e - 0.5f * c15.w;  // d[63][63]; lane63 c15.w = img[63][63]
}

extern "C" void kernel_launch(void* const* d_in, const int* in_sizes, int n_in,
                              void* d_out, int out_size, void* d_ws, size_t ws_size,
                              hipStream_t stream) {
    const float* img = (const float*)d_in[0];
    float* out = (float*)d_out;
    const int B = out_size;                  // 2048
    const int threads = 128;                 // 2 waves (samples) per block
    const int grid = (B + 1) / 2;
    dp_diag_kernel<<<grid, threads, 0, stream>>>(img, out, B);
}